// Round 23
// baseline (276.787 us; speedup 1.0000x reference)
//
#include <hip/hip_runtime.h>

typedef unsigned short u16;
typedef unsigned char  u8;
typedef unsigned int   u32;
typedef __attribute__((ext_vector_type(8))) short short8;
typedef __attribute__((ext_vector_type(4))) float f32x4;

__device__ __forceinline__ float bf2f(u16 u){
  union { u32 i; float f; } v; v.i = ((u32)u) << 16; return v.f;
}
__device__ __forceinline__ u16 f2bf(float f){
  union { float f; u32 i; } v; v.f = f;
  u32 x = v.i;
  x += 0x7fffu + ((x >> 16) & 1u);
  return (u16)(x >> 16);
}
__device__ __forceinline__ float loadin(const void* p, size_t i, int f){
  return f ? ((const float*)p)[i] : bf2f(((const u16*)p)[i]);
}
__device__ __forceinline__ void load8bf(const void* p, size_t i, int f, u16* dst){
  if (f){
    float4 a = *(const float4*)((const float*)p + i);
    float4 b = *(const float4*)((const float*)p + i + 4);
    dst[0]=f2bf(a.x); dst[1]=f2bf(a.y); dst[2]=f2bf(a.z); dst[3]=f2bf(a.w);
    dst[4]=f2bf(b.x); dst[5]=f2bf(b.y); dst[6]=f2bf(b.z); dst[7]=f2bf(b.w);
  } else {
    *(uint4*)dst = *(const uint4*)((const u16*)p + i);
  }
}

// ---------------------------------------------------------------------------
// Sniffer: flg[0] input dtype (1=fp32), flg[1] e8a-is-W_to (ssq 8 vs 64).
// v2: uint4 scan (round-8: scalar u16 loads at VGPR=8 cost 59us for 128KB).
// ---------------------------------------------------------------------------
__global__ __launch_bounds__(256) void k_sniff(
    const u16* __restrict__ x, const void* __restrict__ e8a,
    const void* __restrict__ e8b, u32* __restrict__ flg)
{
  __shared__ int cnt[256];
  __shared__ float red[256];
  __shared__ int fsh;
  const int tid = threadIdx.x;
  int c = 0;
  const uint4* xv = (const uint4*)x;
  #pragma unroll 4
  for (int i = tid; i < 8192; i += 256){
    uint4 v = xv[i];
    c += (((v.x >>  7) & 0xFFu) == 0xFFu);
    c += (((v.x >> 23) & 0xFFu) == 0xFFu);
    c += (((v.y >>  7) & 0xFFu) == 0xFFu);
    c += (((v.y >> 23) & 0xFFu) == 0xFFu);
    c += (((v.z >>  7) & 0xFFu) == 0xFFu);
    c += (((v.z >> 23) & 0xFFu) == 0xFFu);
    c += (((v.w >>  7) & 0xFFu) == 0xFFu);
    c += (((v.w >> 23) & 0xFFu) == 0xFFu);
  }
  cnt[tid] = c;
  __syncthreads();
  for (int s = 128; s > 0; s >>= 1){
    if (tid < s) cnt[tid] += cnt[tid + s];
    __syncthreads();
  }
  if (tid == 0){
    int f = (cnt[0] >= 8) ? 1 : 0;
    flg[0] = (u32)f; fsh = f;
  }
  __syncthreads();
  const int f = fsh;
  float va = loadin(e8a, tid, f), vb = loadin(e8a, tid + 256, f);
  red[tid] = va * va + vb * vb;
  __syncthreads();
  for (int s = 128; s > 0; s >>= 1){
    if (tid < s) red[tid] += red[tid + s];
    __syncthreads();
  }
  if (tid == 0) flg[1] = (red[0] < 30.0f) ? 0u : 1u;
}

// ---------------------------------------------------------------------------
// E8 roots in exact reference order.
// ---------------------------------------------------------------------------
__device__ __forceinline__ void gen_root(int tid, float* v){
  #pragma unroll
  for (int q = 0; q < 8; q++) v[q] = 0.f;
  if (tid < 112){
    int pi = tid >> 2;
    int i = 0, p = pi;
    while (p >= 7 - i){ p -= 7 - i; i++; }
    int j = i + 1 + p;
    v[i] = (tid & 2) ? -1.f : 1.f;
    v[j] = (tid & 1) ? -1.f : 1.f;
  } else {
    int k = tid - 112;
    int mask = 2 * k + (__popc(k) & 1);
    #pragma unroll
    for (int q = 0; q < 8; q++) v[q] = ((mask >> q) & 1) ? -0.5f : 0.5f;
  }
}

__global__ __launch_bounds__(256) void k_prep_qrec(
    const void* __restrict__ e8a, const void* __restrict__ e8b,
    const u32* __restrict__ flg, float* __restrict__ Qrec)
{
  __shared__ float roots[240 * 8];
  __shared__ double wf[512];
  const int f = (int)flg[0], tid = threadIdx.x;
  const void* Wfrom = (flg[1] == 0u) ? e8b : e8a;
  if (tid < 240){
    float v[8];
    gen_root(tid, v);
    #pragma unroll
    for (int q = 0; q < 8; q++) roots[tid * 8 + q] = v[q];
  }
  wf[tid] = (double)loadin(Wfrom, tid, f);
  wf[tid + 256] = (double)loadin(Wfrom, tid + 256, f);
  __syncthreads();
  for (int e = tid; e < 240 * 64; e += 256){
    int r = e >> 6, d = e & 63;
    double acc = 0.0;
    #pragma unroll
    for (int j = 0; j < 8; j++)
      acc = fma((double)roots[r * 8 + j], wf[j * 64 + d], acc);
    Qrec[e] = (float)acc;
  }
}

__global__ __launch_bounds__(256) void k_prep_wqe(
    const void* __restrict__ Wq, const void* __restrict__ e8a,
    const void* __restrict__ e8b, const u32* __restrict__ flg,
    float* __restrict__ Wqe)
{
  __shared__ double wt[512];
  const int f = (int)flg[0], tid = threadIdx.x;
  const void* Wto = (flg[1] == 0u) ? e8a : e8b;
  wt[tid] = (double)loadin(Wto, tid, f);
  wt[tid + 256] = (double)loadin(Wto, tid + 256, f);
  __syncthreads();
  int g = blockIdx.x * 256 + tid;
  int j = g & 7, h = (g >> 3) & 15, d = g >> 7;
  double s = 0.0;
  for (int d2 = 0; d2 < 64; d2++)
    s = fma((double)loadin(Wq, (size_t)d * 1024 + h * 64 + d2, f), wt[d2 * 8 + j], s);
  Wqe[(size_t)d * 128 + h * 8 + j] = (float)s;
}

// ---------------------------------------------------------------------------
// e8 = x @ Wqe, argmin (first-min) -> u8 index.
// v5: fp32 per-slice accumulation (fp64 issue was the limiter), fp64
// cross-slice reduction + argmin. Verified round-11: absmax unchanged.
// ---------------------------------------------------------------------------
__global__ __launch_bounds__(256) void k_qe8(
    const void* __restrict__ x, const u32* __restrict__ flg,
    const float* __restrict__ Wqe, u8* __restrict__ Qidx)
{
  __shared__ float xs[4 * 1088];     // row stride 1088; dim d at d+(d>>6)*4
  __shared__ float roots[240 * 8];
  double* xw   = (double*)xs;        // overlay: [ (wid-1)*16+h ][33] x 48
  double* totb = (double*)xs + 48 * 33;  // overlay: [unit][9] x 64
  const int f = (int)flg[0], tid = threadIdx.x;
  if (tid < 240){
    float v[8];
    gen_root(tid, v);
    #pragma unroll
    for (int q = 0; q < 8; q++) roots[tid * 8 + q] = v[q];
  }
  const int m0 = blockIdx.x * 4;
  // stage 4 rows of x as f32 with per-64-dim skew (+4 floats)
  {
    const int e = tid * 16;
    const int rr = e >> 10, cc = e & 1023;
    const size_t g = (size_t)(m0 + rr) * 1024 + cc;
    float* dstp = xs + rr * 1088 + cc + ((cc >> 6) << 2);
    if (f){
      #pragma unroll
      for (int u = 0; u < 4; u++)
        *(float4*)(dstp + u * 4) = *(const float4*)((const float*)x + g + u * 4);
    } else {
      #pragma unroll
      for (int u = 0; u < 2; u++){
        union { uint4 u4; u16 us[8]; } t;
        t.u4 = *(const uint4*)((const u16*)x + g + u * 8);
        #pragma unroll
        for (int jj = 0; jj < 8; jj++) dstp[u * 8 + jj] = bf2f(t.us[jj]);
      }
    }
  }
  __syncthreads();
  const int h = tid & 15, ks = tid >> 4;   // ks 0..15, 64 dims each
  float acc[4][8];
  #pragma unroll
  for (int r = 0; r < 4; r++)
    #pragma unroll
    for (int j = 0; j < 8; j++) acc[r][j] = 0.f;
  {
    const float* xrow = xs + ks * 68;
    const float* wq = Wqe + (size_t)(ks * 64) * 128 + h * 8;
    for (int d8 = 0; d8 < 64; d8 += 8){
      float xv[4][8];
      #pragma unroll
      for (int r = 0; r < 4; r++){
        *(float4*)(xv[r])     = *(const float4*)(xrow + r * 1088 + d8);
        *(float4*)(xv[r] + 4) = *(const float4*)(xrow + r * 1088 + d8 + 4);
      }
      #pragma unroll
      for (int u = 0; u < 8; u++){
        float wv[8];
        *(float4*)(wv)     = *(const float4*)(wq + (size_t)(d8 + u) * 128);
        *(float4*)(wv + 4) = *(const float4*)(wq + (size_t)(d8 + u) * 128 + 4);
        #pragma unroll
        for (int r = 0; r < 4; r++){
          float xd = xv[r][u];
          #pragma unroll
          for (int j = 0; j < 8; j++)
            acc[r][j] = fmaf(xd, wv[j], acc[r][j]);
        }
      }
    }
  }
  // promote slice sums to fp64; butterfly over ks bits 0,1 (lane bits 4,5)
  double accd[4][8];
  #pragma unroll
  for (int r = 0; r < 4; r++)
    #pragma unroll
    for (int j = 0; j < 8; j++){
      double v = (double)acc[r][j];
      v += __shfl_xor(v, 16);
      v += __shfl_xor(v, 32);
      accd[r][j] = v;
    }
  __syncthreads();                   // all xs reads done -> overlay is safe
  const int lane = tid & 63, wid = tid >> 6;
  if (wid >= 1 && lane < 16){
    double* dst = xw + ((wid - 1) * 16 + lane) * 33;
    #pragma unroll
    for (int r = 0; r < 4; r++)
      #pragma unroll
      for (int j = 0; j < 8; j++) dst[r * 8 + j] = accd[r][j];
  }
  __syncthreads();
  if (wid == 0 && lane < 16){
    #pragma unroll
    for (int r = 0; r < 4; r++)
      #pragma unroll
      for (int j = 0; j < 8; j++){
        double t = (accd[r][j]                   + xw[(lane) * 33 + r * 8 + j])
                 + (xw[(16 + lane) * 33 + r * 8 + j] + xw[(32 + lane) * 33 + r * 8 + j]);
        totb[(r * 16 + lane) * 9 + j] = t;
      }
  }
  __syncthreads();
  // argmin: 4 threads per (row,head) unit, 60 roots each, exact first-min
  const int unit = tid >> 2, s = tid & 3;
  double t8[8];
  #pragma unroll
  for (int j = 0; j < 8; j++) t8[j] = totb[unit * 9 + j];
  double best = 1.0e300; int bi = 0;
  const int rt0 = s * 60;
  for (int rt = rt0; rt < rt0 + 60; rt++){
    const float* rp = roots + rt * 8;
    double d = 0.0;
    #pragma unroll
    for (int j = 0; j < 8; j++) d = fma(t8[j], (double)rp[j], d);
    double sc = -2.0 * d + 2.0;
    if (sc < best){ best = sc; bi = rt; }
  }
  {
    double ob = __shfl_xor(best, 1); int oi = __shfl_xor(bi, 1);
    if (ob < best || (ob == best && oi < bi)){ best = ob; bi = oi; }
    ob = __shfl_xor(best, 2); oi = __shfl_xor(bi, 2);
    if (ob < best || (ob == best && oi < bi)){ best = ob; bi = oi; }
  }
  if (s == 0){
    const int row_local = unit >> 4, hh = unit & 15;
    const int m = m0 + row_local, b = m >> 11, t = m & 2047;
    Qidx[(size_t)(b * 16 + hh) * 2048 + t] = (u8)bi;
  }
}

// ---------------------------------------------------------------------------
// Transpose+convert Wk/Wv/Wout -> bf16 WT [N][K].
// ---------------------------------------------------------------------------
__global__ __launch_bounds__(256) void k_cvt_wT(
    const void* __restrict__ W0, const void* __restrict__ W1,
    const void* __restrict__ W2, const u32* __restrict__ flg,
    u16* __restrict__ WT)
{
  __shared__ u16 Ts[64 * 72];
  const int f = (int)flg[0];
  const void* src = (blockIdx.y == 0) ? W0 : (blockIdx.y == 1) ? W1 : W2;
  u16* dst = WT + (size_t)blockIdx.y * (1024 * 1024);
  const int rt = blockIdx.x >> 4, ct = blockIdx.x & 15;
  const int tid = threadIdx.x;
  #pragma unroll
  for (int half = 0; half < 2; half++){
    int c = tid + half * 256;
    int r = c >> 3, cc = (c & 7) * 8;
    u16 t8[8];
    load8bf(src, (size_t)(rt * 64 + r) * 1024 + ct * 64 + cc, f, t8);
    *(uint4*)(Ts + r * 72 + cc) = *(uint4*)t8;
  }
  __syncthreads();
  #pragma unroll
  for (int half = 0; half < 2; half++){
    int c = tid + half * 256;
    int r = c >> 3, cc = (c & 7) * 8;
    union { uint4 u4; u16 us[8]; } t;
    #pragma unroll
    for (int jj = 0; jj < 8; jj++) t.us[jj] = Ts[(cc + jj) * 72 + r];
    *(uint4*)(dst + (size_t)(ct * 64 + r) * 1024 + rt * 64 + cc) = t.u4;
  }
}

// ---------------------------------------------------------------------------
// 128x128 MFMA GEMM core v2: double-buffered LDS + async-stage split.
// ---------------------------------------------------------------------------
__device__ __forceinline__ void gemm_core_bt(
    const void* __restrict__ A, int af, const u16* __restrict__ Bt,
    u16* lds, int bm, int bn, f32x4 (&acc)[4][4])
{
  u16* As0 = lds;
  u16* Bs0 = lds + 5120;
  u16* As1 = lds + 10240;
  u16* Bs1 = lds + 15360;
  const int tid = threadIdx.x;
  const int lane = tid & 63, w = tid >> 6;
  const int wm = w >> 1, wn = w & 1, quad = lane >> 4, l15 = lane & 15;
  #pragma unroll
  for (int mt = 0; mt < 4; mt++)
    #pragma unroll
    for (int nt = 0; nt < 4; nt++) acc[mt][nt] = (f32x4){0.f, 0.f, 0.f, 0.f};
  const int r0 = tid >> 2, c0 = (tid & 3) * 8;
  const size_t aRow0 = (size_t)(bm * 128 + r0) * 1024 + c0;
  const size_t aRow1 = (size_t)(bm * 128 + r0 + 64) * 1024 + c0;
  const u16* Br0 = Bt + (size_t)(bn * 128 + r0) * 1024 + c0;
  const u16* Br1 = Bt + (size_t)(bn * 128 + r0 + 64) * 1024 + c0;
  const int wA0 = r0 * 40 + c0, wA1 = (r0 + 64) * 40 + c0;
  // prologue: stage K-step 0 into buffer 0
  {
    u16 a0[8], a1[8];
    load8bf(A, aRow0, af, a0);
    load8bf(A, aRow1, af, a1);
    uint4 b0 = *(const uint4*)(Br0);
    uint4 b1 = *(const uint4*)(Br1);
    *(uint4*)(As0 + wA0) = *(uint4*)a0;
    *(uint4*)(As0 + wA1) = *(uint4*)a1;
    *(uint4*)(Bs0 + wA0) = b0;
    *(uint4*)(Bs0 + wA1) = b1;
  }
  __syncthreads();
  for (int k0 = 0; k0 < 1024; k0 += 32){
    const int cur = (k0 >> 5) & 1;
    u16* Asc = cur ? As1 : As0;
    u16* Bsc = cur ? Bs1 : Bs0;
    u16* Asn = cur ? As0 : As1;
    u16* Bsn = cur ? Bs0 : Bs1;
    const bool pf = (k0 + 32 < 1024);
    u16 na0[8], na1[8];
    uint4 nb0, nb1;
    if (pf){                          // issue next-step loads EARLY
      load8bf(A, aRow0 + k0 + 32, af, na0);
      load8bf(A, aRow1 + k0 + 32, af, na1);
      nb0 = *(const uint4*)(Br0 + k0 + 32);
      nb1 = *(const uint4*)(Br1 + k0 + 32);
    }
    short8 afr[4];
    #pragma unroll
    for (int mt = 0; mt < 4; mt++)
      afr[mt] = *(const short8*)(Asc + (wm * 64 + mt * 16 + l15) * 40 + quad * 8);
    #pragma unroll
    for (int nt = 0; nt < 4; nt++){
      short8 bfr = *(const short8*)(Bsc + (wn * 64 + nt * 16 + l15) * 40 + quad * 8);
      #pragma unroll
      for (int mt = 0; mt < 4; mt++)
        acc[mt][nt] = __builtin_amdgcn_mfma_f32_16x16x32_bf16(afr[mt], bfr, acc[mt][nt], 0, 0, 0);
    }
    if (pf){                          // write next step into inactive buffer
      *(uint4*)(Asn + wA0) = *(uint4*)na0;
      *(uint4*)(Asn + wA1) = *(uint4*)na1;
      *(uint4*)(Bsn + wA0) = nb0;
      *(uint4*)(Bsn + wA1) = nb1;
    }
    __syncthreads();                  // single barrier per K-step
  }
}

// K/V projection. z=0 -> Kb [b,h,t,d]; z=1 -> Vt [b,h,d,t] DIRECTLY
// (round-15: k_vt eliminated; verified round-21, absmax unchanged).
__global__ __launch_bounds__(256) void k_gemm_kv(
    const void* __restrict__ X, const u16* __restrict__ WkT,
    const u16* __restrict__ WvT, const u32* __restrict__ flg,
    u16* __restrict__ Kb, u16* __restrict__ Vt)
{
  __shared__ u16 lds[20480];          // 40960 B, double-buffered
  const int f = (int)flg[0];
  const u16* Bt = (blockIdx.z == 0) ? WkT : WvT;
  f32x4 acc[4][4];
  gemm_core_bt(X, f, Bt, lds, blockIdx.y, blockIdx.x, acc);
  const int tid = threadIdx.x, lane = tid & 63, w = tid >> 6;
  const int wm = w >> 1, wn = w & 1, quad = lane >> 4, l15 = lane & 15;
  if (blockIdx.z == 0){
    #pragma unroll
    for (int mt = 0; mt < 4; mt++)
      #pragma unroll
      for (int nt = 0; nt < 4; nt++)
        #pragma unroll
        for (int rr = 0; rr < 4; rr++){
          int m = blockIdx.y * 128 + wm * 64 + mt * 16 + quad * 4 + rr;
          int n = blockIdx.x * 128 + wn * 64 + nt * 16 + l15;
          int b = m >> 11, t = m & 2047, h = n >> 6, d = n & 63;
          Kb[((size_t)(b * 16 + h) * 2048 + t) * 64 + d] = f2bf(acc[mt][nt][rr]);
        }
  } else {
    #pragma unroll
    for (int mt = 0; mt < 4; mt++)
      #pragma unroll
      for (int nt = 0; nt < 4; nt++){
        u16 four[4];
        #pragma unroll
        for (int rr = 0; rr < 4; rr++) four[rr] = f2bf(acc[mt][nt][rr]);
        int m = blockIdx.y * 128 + wm * 64 + mt * 16 + quad * 4;   // rr = 0
        int n = blockIdx.x * 128 + wn * 64 + nt * 16 + l15;
        int b = m >> 11, t = m & 2047, h = n >> 6, d = n & 63;
        *(uint2*)(Vt + ((size_t)(b * 16 + h) * 64 + d) * 2048 + t) = *(uint2*)four;
      }
  }
}

// Output projection: AO(bf16) @ WoutT -> FP32 d_out.
__global__ __launch_bounds__(256) void k_gemm_out(
    const u16* __restrict__ A, const u16* __restrict__ WoutT,
    float* __restrict__ O)
{
  __shared__ u16 lds[20480];          // 40960 B, double-buffered
  f32x4 acc[4][4];
  gemm_core_bt(A, 0, WoutT, lds, blockIdx.y, blockIdx.x, acc);
  const int tid = threadIdx.x, lane = tid & 63, w = tid >> 6;
  const int wm = w >> 1, wn = w & 1, quad = lane >> 4, l15 = lane & 15;
  #pragma unroll
  for (int mt = 0; mt < 4; mt++)
    #pragma unroll
    for (int nt = 0; nt < 4; nt++)
      #pragma unroll
      for (int rr = 0; rr < 4; rr++){
        int m = blockIdx.y * 128 + wm * 64 + mt * 16 + quad * 4 + rr;
        int n = blockIdx.x * 128 + wn * 64 + nt * 16 + l15;
        O[(size_t)m * 1024 + n] = acc[mt][nt][rr];
      }
}

// ---------------------------------------------------------------------------
// MFMA causal flash v6: un-paired q-tiles + LPT dispatch order.
// Round-21 counters: occ 18% (grid 512 = 2 blocks/CU), MfmaUtil 11%,
// VALU 29% -- latency-bound with every barrier stalling half the CU.
// Now: grid (32,32), ONE qt per block, qt = 31 - bx so the LONGEST blocks
// (qt=31: 32 kt-iters) dispatch first and short ones backfill (LPT order;
// the qt-ascending imbalance that motivated pairing is thereby fixed).
// 1024 blocks -> LDS (46KB) allows 3 resident blocks/CU = 12 waves/CU
// (was 8), and independent blocks overlap across barriers.
// Inner loop/LDS/math byte-identical to v4.
// ---------------------------------------------------------------------------
__global__ __launch_bounds__(256) void k_flash(
    const u8* __restrict__ Qidx, const float* __restrict__ Qrec,
    const u16* __restrict__ Kb, const u16* __restrict__ Vt,
    u16* __restrict__ AO)
{
  __shared__ u16 lds[23040];        // 46080 B
  u16* Ks0 = lds;                   // [64 key][72: d]
  u16* Ks1 = lds + 4608;
  u16* Vs0 = lds + 9216;            // [64 d][72: key]
  u16* Vs1 = lds + 13824;
  u16* Ps  = lds + 18432;           // 4 waves x [16 q][72: key] (wave-private)
  const int tid = threadIdx.x;
  const int lane = tid & 63, w = tid >> 6, quad = lane >> 4, l15 = lane & 15;
  const int qt = 31 - blockIdx.x;   // LPT: longest blocks first
  const int bh = blockIdx.y;
  const size_t baseK = (size_t)bh * (2048 * 64);
  const size_t baseV = (size_t)bh * (64 * 2048);
  const int sr = tid >> 3, sc = (tid & 7) * 8;
  const int b = bh >> 4, h = bh & 15;
  u16* Pw = Ps + w * (16 * 72);
  {
    // Q fragments from the 240x64 reconstruction table
    const int qrowA = qt * 64 + w * 16 + l15;
    const int qi = Qidx[bh * 2048 + qrowA];
    const float* qr = Qrec + qi * 64;
    u16 qtmp[8];
    float4 qa = *(const float4*)(qr + quad * 8);
    float4 qb = *(const float4*)(qr + quad * 8 + 4);
    qtmp[0]=f2bf(qa.x); qtmp[1]=f2bf(qa.y); qtmp[2]=f2bf(qa.z); qtmp[3]=f2bf(qa.w);
    qtmp[4]=f2bf(qb.x); qtmp[5]=f2bf(qb.y); qtmp[6]=f2bf(qb.z); qtmp[7]=f2bf(qb.w);
    short8 aq0 = *(short8*)qtmp;
    qa = *(const float4*)(qr + 32 + quad * 8);
    qb = *(const float4*)(qr + 32 + quad * 8 + 4);
    qtmp[0]=f2bf(qa.x); qtmp[1]=f2bf(qa.y); qtmp[2]=f2bf(qa.z); qtmp[3]=f2bf(qa.w);
    qtmp[4]=f2bf(qb.x); qtmp[5]=f2bf(qb.y); qtmp[6]=f2bf(qb.z); qtmp[7]=f2bf(qb.w);
    short8 aq1 = *(short8*)qtmp;
    f32x4 o[4];
    #pragma unroll
    for (int nt = 0; nt < 4; nt++) o[nt] = (f32x4){0.f, 0.f, 0.f, 0.f};
    float lpart[4] = {0.f, 0.f, 0.f, 0.f};
    const int qrow_q = qt * 64 + w * 16 + quad * 4;
    // prologue: stage tile 0 into buffer 0
    #pragma unroll
    for (int half = 0; half < 2; half++){
      int r = sr + half * 32;
      *(uint4*)(Ks0 + r * 72 + sc) =
          *(const uint4*)(Kb + baseK + (size_t)r * 64 + sc);
      *(uint4*)(Vs0 + r * 72 + sc) =
          *(const uint4*)(Vt + baseV + (size_t)r * 2048 + sc);
    }
    __syncthreads();
    for (int kt = 0; kt <= qt; kt++){
      const int kbase = kt * 64;
      const int cur = kt & 1;
      u16* Kc = cur ? Ks1 : Ks0;
      u16* Vc = cur ? Vs1 : Vs0;
      u16* Kn = cur ? Ks0 : Ks1;
      u16* Vn = cur ? Vs0 : Vs1;
      const bool pf = (kt < qt);
      uint4 kr0, kr1, vr0, vr1;
      if (pf){                       // issue next-tile loads EARLY (T14)
        const int nb = kbase + 64;
        kr0 = *(const uint4*)(Kb + baseK + (size_t)(nb + sr) * 64 + sc);
        kr1 = *(const uint4*)(Kb + baseK + (size_t)(nb + sr + 32) * 64 + sc);
        vr0 = *(const uint4*)(Vt + baseV + (size_t)sr * 2048 + nb + sc);
        vr1 = *(const uint4*)(Vt + baseV + (size_t)(sr + 32) * 2048 + nb + sc);
      }
      f32x4 s[4];
      #pragma unroll
      for (int nt = 0; nt < 4; nt++){
        s[nt] = (f32x4){0.f, 0.f, 0.f, 0.f};
        short8 bk0 = *(const short8*)(Kc + (nt * 16 + l15) * 72 + quad * 8);
        short8 bk1 = *(const short8*)(Kc + (nt * 16 + l15) * 72 + 32 + quad * 8);
        s[nt] = __builtin_amdgcn_mfma_f32_16x16x32_bf16(aq0, bk0, s[nt], 0, 0, 0);
        s[nt] = __builtin_amdgcn_mfma_f32_16x16x32_bf16(aq1, bk1, s[nt], 0, 0, 0);
      }
      if (kt == qt){
        #pragma unroll
        for (int rr = 0; rr < 4; rr++)
          #pragma unroll
          for (int nt = 0; nt < 4; nt++){
            float p = (kbase + nt * 16 + l15 > qrow_q + rr)
                        ? 0.f : __expf(s[nt][rr] * 0.125f - 16.0f);
            lpart[rr] += p;
            Pw[(quad * 4 + rr) * 72 + nt * 16 + l15] = f2bf(p);
          }
      } else {
        #pragma unroll
        for (int rr = 0; rr < 4; rr++)
          #pragma unroll
          for (int nt = 0; nt < 4; nt++){
            float p = __expf(s[nt][rr] * 0.125f - 16.0f);
            lpart[rr] += p;
            Pw[(quad * 4 + rr) * 72 + nt * 16 + l15] = f2bf(p);
          }
      }
      #pragma unroll
      for (int ks = 0; ks < 2; ks++){
        short8 pa = *(const short8*)(Pw + l15 * 72 + ks * 32 + quad * 8);
        #pragma unroll
        for (int nt = 0; nt < 4; nt++){
          short8 vbf = *(const short8*)(Vc + (nt * 16 + l15) * 72 + ks * 32 + quad * 8);
          o[nt] = __builtin_amdgcn_mfma_f32_16x16x32_bf16(pa, vbf, o[nt], 0, 0, 0);
        }
      }
      if (pf){                       // write next tile into inactive buffer
        *(uint4*)(Kn + sr * 72 + sc) = kr0;
        *(uint4*)(Kn + (sr + 32) * 72 + sc) = kr1;
        *(uint4*)(Vn + sr * 72 + sc) = vr0;
        *(uint4*)(Vn + (sr + 32) * 72 + sc) = vr1;
      }
      __syncthreads();               // single barrier per kt
    }
    // one-time l reduction across the 16 column-lanes
    float linv[4];
    #pragma unroll
    for (int rr = 0; rr < 4; rr++){
      float L = lpart[rr];
      L += __shfl_xor(L, 1); L += __shfl_xor(L, 2);
      L += __shfl_xor(L, 4); L += __shfl_xor(L, 8);
      linv[rr] = 1.0f / L;
    }
    #pragma unroll
    for (int rr = 0; rr < 4; rr++){
      int qrow = qrow_q + rr;
      #pragma unroll
      for (int nt = 0; nt < 4; nt++){
        float v = o[nt][rr] * linv[rr];
        AO[(size_t)(b * 2048 + qrow) * 1024 + h * 64 + nt * 16 + l15] = f2bf(v);
      }
    }
  }
}

extern "C" void kernel_launch(void* const* d_in, const int* in_sizes, int n_in,
                              void* d_out, int out_size, void* d_ws, size_t ws_size,
                              hipStream_t stream)
{
  int ix = -1, ibig[8], nbig = 0, i512[8], n512 = 0;
  for (int i = 0; i < n_in; i++){
    if (in_sizes[i] == 4194304) ix = i;
    else if (in_sizes[i] == 1048576){ if (nbig < 8) ibig[nbig++] = i; }
    else if (in_sizes[i] == 512){ if (n512 < 8) i512[n512++] = i; }
  }
  const void *x, *Wq, *Wk, *Wv, *Wout, *e8a, *e8b;
  if (ix >= 0 && nbig == 4 && n512 == 2){
    x = d_in[ix];
    e8a = d_in[i512[0]]; e8b = d_in[i512[1]];
    bool alpha = (i512[0] == 0 && i512[1] == 1 && ix == n_in - 1);
    if (alpha){
      Wk = d_in[ibig[0]]; Wout = d_in[ibig[1]];
      Wq = d_in[ibig[2]]; Wv   = d_in[ibig[3]];
    } else {
      Wq = d_in[ibig[0]]; Wk   = d_in[ibig[1]];
      Wv = d_in[ibig[2]]; Wout = d_in[ibig[3]];
    }
  } else {
    x = d_in[0]; Wq = d_in[1]; Wk = d_in[2]; Wv = d_in[3];
    e8a = d_in[4]; e8b = d_in[5]; Wout = d_in[6];
  }
  float* out = (float*)d_out;
  char* ws = (char*)d_ws;

  // ws layout -- 39 MB
  u32*   flg  = (u32*)  (ws);
  float* Qrec = (float*)(ws + 4096);
  u8*    Qidx = (u8*)   (ws + 69632);
  float* Wqe  = (float*)(ws + 147456);
  u16*   WT   = (u16*)  (ws + 1048576);
  u16*   Kb   = (u16*)  (ws + 7340032);
  u16*   Vt   = (u16*)  (ws + 24117248);
  u16*   AO   = (u16*)  (ws + 32505856);

  k_sniff<<<dim3(1), dim3(256), 0, stream>>>((const u16*)x, e8a, e8b, flg);
  k_prep_qrec<<<dim3(1), dim3(256), 0, stream>>>(e8a, e8b, flg, Qrec);
  k_prep_wqe<<<dim3(512), dim3(256), 0, stream>>>(Wq, e8a, e8b, flg, Wqe);
  k_qe8<<<dim3(1024), dim3(256), 0, stream>>>(x, flg, Wqe, Qidx);
  k_cvt_wT<<<dim3(256, 3), dim3(256), 0, stream>>>(Wk, Wv, Wout, flg, WT);
  k_gemm_kv<<<dim3(8, 32, 2), dim3(256), 0, stream>>>(
      x, WT, WT + 1048576, flg, Kb, Vt);
  k_flash<<<dim3(32, 32), dim3(256), 0, stream>>>(Qidx, Qrec, Kb, Vt, AO);
  k_gemm_out<<<dim3(8, 32), dim3(256), 0, stream>>>(AO, WT + 2097152, out);
}

// Round 24
// 250.098 us; speedup vs baseline: 1.1067x; 1.1067x over previous
//
#include <hip/hip_runtime.h>

typedef unsigned short u16;
typedef unsigned char  u8;
typedef unsigned int   u32;
typedef __attribute__((ext_vector_type(8))) short short8;
typedef __attribute__((ext_vector_type(4))) float f32x4;

__device__ __forceinline__ float bf2f(u16 u){
  union { u32 i; float f; } v; v.i = ((u32)u) << 16; return v.f;
}
__device__ __forceinline__ u16 f2bf(float f){
  union { float f; u32 i; } v; v.f = f;
  u32 x = v.i;
  x += 0x7fffu + ((x >> 16) & 1u);
  return (u16)(x >> 16);
}
__device__ __forceinline__ float loadin(const void* p, size_t i, int f){
  return f ? ((const float*)p)[i] : bf2f(((const u16*)p)[i]);
}
__device__ __forceinline__ void load8bf(const void* p, size_t i, int f, u16* dst){
  if (f){
    float4 a = *(const float4*)((const float*)p + i);
    float4 b = *(const float4*)((const float*)p + i + 4);
    dst[0]=f2bf(a.x); dst[1]=f2bf(a.y); dst[2]=f2bf(a.z); dst[3]=f2bf(a.w);
    dst[4]=f2bf(b.x); dst[5]=f2bf(b.y); dst[6]=f2bf(b.z); dst[7]=f2bf(b.w);
  } else {
    *(uint4*)dst = *(const uint4*)((const u16*)p + i);
  }
}

// ---------------------------------------------------------------------------
// Sniffer: flg[0] input dtype (1=fp32), flg[1] e8a-is-W_to (ssq 8 vs 64).
// v2: uint4 scan (round-8: scalar u16 loads at VGPR=8 cost 59us for 128KB).
// ---------------------------------------------------------------------------
__global__ __launch_bounds__(256) void k_sniff(
    const u16* __restrict__ x, const void* __restrict__ e8a,
    const void* __restrict__ e8b, u32* __restrict__ flg)
{
  __shared__ int cnt[256];
  __shared__ float red[256];
  __shared__ int fsh;
  const int tid = threadIdx.x;
  int c = 0;
  const uint4* xv = (const uint4*)x;
  #pragma unroll 4
  for (int i = tid; i < 8192; i += 256){
    uint4 v = xv[i];
    c += (((v.x >>  7) & 0xFFu) == 0xFFu);
    c += (((v.x >> 23) & 0xFFu) == 0xFFu);
    c += (((v.y >>  7) & 0xFFu) == 0xFFu);
    c += (((v.y >> 23) & 0xFFu) == 0xFFu);
    c += (((v.z >>  7) & 0xFFu) == 0xFFu);
    c += (((v.z >> 23) & 0xFFu) == 0xFFu);
    c += (((v.w >>  7) & 0xFFu) == 0xFFu);
    c += (((v.w >> 23) & 0xFFu) == 0xFFu);
  }
  cnt[tid] = c;
  __syncthreads();
  for (int s = 128; s > 0; s >>= 1){
    if (tid < s) cnt[tid] += cnt[tid + s];
    __syncthreads();
  }
  if (tid == 0){
    int f = (cnt[0] >= 8) ? 1 : 0;
    flg[0] = (u32)f; fsh = f;
  }
  __syncthreads();
  const int f = fsh;
  float va = loadin(e8a, tid, f), vb = loadin(e8a, tid + 256, f);
  red[tid] = va * va + vb * vb;
  __syncthreads();
  for (int s = 128; s > 0; s >>= 1){
    if (tid < s) red[tid] += red[tid + s];
    __syncthreads();
  }
  if (tid == 0) flg[1] = (red[0] < 30.0f) ? 0u : 1u;
}

// ---------------------------------------------------------------------------
// E8 roots in exact reference order.
// ---------------------------------------------------------------------------
__device__ __forceinline__ void gen_root(int tid, float* v){
  #pragma unroll
  for (int q = 0; q < 8; q++) v[q] = 0.f;
  if (tid < 112){
    int pi = tid >> 2;
    int i = 0, p = pi;
    while (p >= 7 - i){ p -= 7 - i; i++; }
    int j = i + 1 + p;
    v[i] = (tid & 2) ? -1.f : 1.f;
    v[j] = (tid & 1) ? -1.f : 1.f;
  } else {
    int k = tid - 112;
    int mask = 2 * k + (__popc(k) & 1);
    #pragma unroll
    for (int q = 0; q < 8; q++) v[q] = ((mask >> q) & 1) ? -0.5f : 0.5f;
  }
}

__global__ __launch_bounds__(256) void k_prep_qrec(
    const void* __restrict__ e8a, const void* __restrict__ e8b,
    const u32* __restrict__ flg, float* __restrict__ Qrec)
{
  __shared__ float roots[240 * 8];
  __shared__ double wf[512];
  const int f = (int)flg[0], tid = threadIdx.x;
  const void* Wfrom = (flg[1] == 0u) ? e8b : e8a;
  if (tid < 240){
    float v[8];
    gen_root(tid, v);
    #pragma unroll
    for (int q = 0; q < 8; q++) roots[tid * 8 + q] = v[q];
  }
  wf[tid] = (double)loadin(Wfrom, tid, f);
  wf[tid + 256] = (double)loadin(Wfrom, tid + 256, f);
  __syncthreads();
  for (int e = tid; e < 240 * 64; e += 256){
    int r = e >> 6, d = e & 63;
    double acc = 0.0;
    #pragma unroll
    for (int j = 0; j < 8; j++)
      acc = fma((double)roots[r * 8 + j], wf[j * 64 + d], acc);
    Qrec[e] = (float)acc;
  }
}

__global__ __launch_bounds__(256) void k_prep_wqe(
    const void* __restrict__ Wq, const void* __restrict__ e8a,
    const void* __restrict__ e8b, const u32* __restrict__ flg,
    float* __restrict__ Wqe)
{
  __shared__ double wt[512];
  const int f = (int)flg[0], tid = threadIdx.x;
  const void* Wto = (flg[1] == 0u) ? e8a : e8b;
  wt[tid] = (double)loadin(Wto, tid, f);
  wt[tid + 256] = (double)loadin(Wto, tid + 256, f);
  __syncthreads();
  int g = blockIdx.x * 256 + tid;
  int j = g & 7, h = (g >> 3) & 15, d = g >> 7;
  double s = 0.0;
  for (int d2 = 0; d2 < 64; d2++)
    s = fma((double)loadin(Wq, (size_t)d * 1024 + h * 64 + d2, f), wt[d2 * 8 + j], s);
  Wqe[(size_t)d * 128 + h * 8 + j] = (float)s;
}

// ---------------------------------------------------------------------------
// e8 = x @ Wqe, argmin (first-min) -> u8 index.
// v5: fp32 per-slice accumulation (fp64 issue was the limiter), fp64
// cross-slice reduction + argmin. Verified round-11: absmax unchanged.
// ---------------------------------------------------------------------------
__global__ __launch_bounds__(256) void k_qe8(
    const void* __restrict__ x, const u32* __restrict__ flg,
    const float* __restrict__ Wqe, u8* __restrict__ Qidx)
{
  __shared__ float xs[4 * 1088];     // row stride 1088; dim d at d+(d>>6)*4
  __shared__ float roots[240 * 8];
  double* xw   = (double*)xs;        // overlay: [ (wid-1)*16+h ][33] x 48
  double* totb = (double*)xs + 48 * 33;  // overlay: [unit][9] x 64
  const int f = (int)flg[0], tid = threadIdx.x;
  if (tid < 240){
    float v[8];
    gen_root(tid, v);
    #pragma unroll
    for (int q = 0; q < 8; q++) roots[tid * 8 + q] = v[q];
  }
  const int m0 = blockIdx.x * 4;
  // stage 4 rows of x as f32 with per-64-dim skew (+4 floats)
  {
    const int e = tid * 16;
    const int rr = e >> 10, cc = e & 1023;
    const size_t g = (size_t)(m0 + rr) * 1024 + cc;
    float* dstp = xs + rr * 1088 + cc + ((cc >> 6) << 2);
    if (f){
      #pragma unroll
      for (int u = 0; u < 4; u++)
        *(float4*)(dstp + u * 4) = *(const float4*)((const float*)x + g + u * 4);
    } else {
      #pragma unroll
      for (int u = 0; u < 2; u++){
        union { uint4 u4; u16 us[8]; } t;
        t.u4 = *(const uint4*)((const u16*)x + g + u * 8);
        #pragma unroll
        for (int jj = 0; jj < 8; jj++) dstp[u * 8 + jj] = bf2f(t.us[jj]);
      }
    }
  }
  __syncthreads();
  const int h = tid & 15, ks = tid >> 4;   // ks 0..15, 64 dims each
  float acc[4][8];
  #pragma unroll
  for (int r = 0; r < 4; r++)
    #pragma unroll
    for (int j = 0; j < 8; j++) acc[r][j] = 0.f;
  {
    const float* xrow = xs + ks * 68;
    const float* wq = Wqe + (size_t)(ks * 64) * 128 + h * 8;
    for (int d8 = 0; d8 < 64; d8 += 8){
      float xv[4][8];
      #pragma unroll
      for (int r = 0; r < 4; r++){
        *(float4*)(xv[r])     = *(const float4*)(xrow + r * 1088 + d8);
        *(float4*)(xv[r] + 4) = *(const float4*)(xrow + r * 1088 + d8 + 4);
      }
      #pragma unroll
      for (int u = 0; u < 8; u++){
        float wv[8];
        *(float4*)(wv)     = *(const float4*)(wq + (size_t)(d8 + u) * 128);
        *(float4*)(wv + 4) = *(const float4*)(wq + (size_t)(d8 + u) * 128 + 4);
        #pragma unroll
        for (int r = 0; r < 4; r++){
          float xd = xv[r][u];
          #pragma unroll
          for (int j = 0; j < 8; j++)
            acc[r][j] = fmaf(xd, wv[j], acc[r][j]);
        }
      }
    }
  }
  // promote slice sums to fp64; butterfly over ks bits 0,1 (lane bits 4,5)
  double accd[4][8];
  #pragma unroll
  for (int r = 0; r < 4; r++)
    #pragma unroll
    for (int j = 0; j < 8; j++){
      double v = (double)acc[r][j];
      v += __shfl_xor(v, 16);
      v += __shfl_xor(v, 32);
      accd[r][j] = v;
    }
  __syncthreads();                   // all xs reads done -> overlay is safe
  const int lane = tid & 63, wid = tid >> 6;
  if (wid >= 1 && lane < 16){
    double* dst = xw + ((wid - 1) * 16 + lane) * 33;
    #pragma unroll
    for (int r = 0; r < 4; r++)
      #pragma unroll
      for (int j = 0; j < 8; j++) dst[r * 8 + j] = accd[r][j];
  }
  __syncthreads();
  if (wid == 0 && lane < 16){
    #pragma unroll
    for (int r = 0; r < 4; r++)
      #pragma unroll
      for (int j = 0; j < 8; j++){
        double t = (accd[r][j]                   + xw[(lane) * 33 + r * 8 + j])
                 + (xw[(16 + lane) * 33 + r * 8 + j] + xw[(32 + lane) * 33 + r * 8 + j]);
        totb[(r * 16 + lane) * 9 + j] = t;
      }
  }
  __syncthreads();
  // argmin: 4 threads per (row,head) unit, 60 roots each, exact first-min
  const int unit = tid >> 2, s = tid & 3;
  double t8[8];
  #pragma unroll
  for (int j = 0; j < 8; j++) t8[j] = totb[unit * 9 + j];
  double best = 1.0e300; int bi = 0;
  const int rt0 = s * 60;
  for (int rt = rt0; rt < rt0 + 60; rt++){
    const float* rp = roots + rt * 8;
    double d = 0.0;
    #pragma unroll
    for (int j = 0; j < 8; j++) d = fma(t8[j], (double)rp[j], d);
    double sc = -2.0 * d + 2.0;
    if (sc < best){ best = sc; bi = rt; }
  }
  {
    double ob = __shfl_xor(best, 1); int oi = __shfl_xor(bi, 1);
    if (ob < best || (ob == best && oi < bi)){ best = ob; bi = oi; }
    ob = __shfl_xor(best, 2); oi = __shfl_xor(bi, 2);
    if (ob < best || (ob == best && oi < bi)){ best = ob; bi = oi; }
  }
  if (s == 0){
    const int row_local = unit >> 4, hh = unit & 15;
    const int m = m0 + row_local, b = m >> 11, t = m & 2047;
    Qidx[(size_t)(b * 16 + hh) * 2048 + t] = (u8)bi;
  }
}

// ---------------------------------------------------------------------------
// Transpose+convert Wk/Wv/Wout -> bf16 WT [N][K].
// ---------------------------------------------------------------------------
__global__ __launch_bounds__(256) void k_cvt_wT(
    const void* __restrict__ W0, const void* __restrict__ W1,
    const void* __restrict__ W2, const u32* __restrict__ flg,
    u16* __restrict__ WT)
{
  __shared__ u16 Ts[64 * 72];
  const int f = (int)flg[0];
  const void* src = (blockIdx.y == 0) ? W0 : (blockIdx.y == 1) ? W1 : W2;
  u16* dst = WT + (size_t)blockIdx.y * (1024 * 1024);
  const int rt = blockIdx.x >> 4, ct = blockIdx.x & 15;
  const int tid = threadIdx.x;
  #pragma unroll
  for (int half = 0; half < 2; half++){
    int c = tid + half * 256;
    int r = c >> 3, cc = (c & 7) * 8;
    u16 t8[8];
    load8bf(src, (size_t)(rt * 64 + r) * 1024 + ct * 64 + cc, f, t8);
    *(uint4*)(Ts + r * 72 + cc) = *(uint4*)t8;
  }
  __syncthreads();
  #pragma unroll
  for (int half = 0; half < 2; half++){
    int c = tid + half * 256;
    int r = c >> 3, cc = (c & 7) * 8;
    union { uint4 u4; u16 us[8]; } t;
    #pragma unroll
    for (int jj = 0; jj < 8; jj++) t.us[jj] = Ts[(cc + jj) * 72 + r];
    *(uint4*)(dst + (size_t)(ct * 64 + r) * 1024 + rt * 64 + cc) = t.u4;
  }
}

// ---------------------------------------------------------------------------
// 128x128 MFMA GEMM core v2: double-buffered LDS + async-stage split.
// ---------------------------------------------------------------------------
__device__ __forceinline__ void gemm_core_bt(
    const void* __restrict__ A, int af, const u16* __restrict__ Bt,
    u16* lds, int bm, int bn, f32x4 (&acc)[4][4])
{
  u16* As0 = lds;
  u16* Bs0 = lds + 5120;
  u16* As1 = lds + 10240;
  u16* Bs1 = lds + 15360;
  const int tid = threadIdx.x;
  const int lane = tid & 63, w = tid >> 6;
  const int wm = w >> 1, wn = w & 1, quad = lane >> 4, l15 = lane & 15;
  #pragma unroll
  for (int mt = 0; mt < 4; mt++)
    #pragma unroll
    for (int nt = 0; nt < 4; nt++) acc[mt][nt] = (f32x4){0.f, 0.f, 0.f, 0.f};
  const int r0 = tid >> 2, c0 = (tid & 3) * 8;
  const size_t aRow0 = (size_t)(bm * 128 + r0) * 1024 + c0;
  const size_t aRow1 = (size_t)(bm * 128 + r0 + 64) * 1024 + c0;
  const u16* Br0 = Bt + (size_t)(bn * 128 + r0) * 1024 + c0;
  const u16* Br1 = Bt + (size_t)(bn * 128 + r0 + 64) * 1024 + c0;
  const int wA0 = r0 * 40 + c0, wA1 = (r0 + 64) * 40 + c0;
  // prologue: stage K-step 0 into buffer 0
  {
    u16 a0[8], a1[8];
    load8bf(A, aRow0, af, a0);
    load8bf(A, aRow1, af, a1);
    uint4 b0 = *(const uint4*)(Br0);
    uint4 b1 = *(const uint4*)(Br1);
    *(uint4*)(As0 + wA0) = *(uint4*)a0;
    *(uint4*)(As0 + wA1) = *(uint4*)a1;
    *(uint4*)(Bs0 + wA0) = b0;
    *(uint4*)(Bs0 + wA1) = b1;
  }
  __syncthreads();
  for (int k0 = 0; k0 < 1024; k0 += 32){
    const int cur = (k0 >> 5) & 1;
    u16* Asc = cur ? As1 : As0;
    u16* Bsc = cur ? Bs1 : Bs0;
    u16* Asn = cur ? As0 : As1;
    u16* Bsn = cur ? Bs0 : Bs1;
    const bool pf = (k0 + 32 < 1024);
    u16 na0[8], na1[8];
    uint4 nb0, nb1;
    if (pf){                          // issue next-step loads EARLY
      load8bf(A, aRow0 + k0 + 32, af, na0);
      load8bf(A, aRow1 + k0 + 32, af, na1);
      nb0 = *(const uint4*)(Br0 + k0 + 32);
      nb1 = *(const uint4*)(Br1 + k0 + 32);
    }
    short8 afr[4];
    #pragma unroll
    for (int mt = 0; mt < 4; mt++)
      afr[mt] = *(const short8*)(Asc + (wm * 64 + mt * 16 + l15) * 40 + quad * 8);
    #pragma unroll
    for (int nt = 0; nt < 4; nt++){
      short8 bfr = *(const short8*)(Bsc + (wn * 64 + nt * 16 + l15) * 40 + quad * 8);
      #pragma unroll
      for (int mt = 0; mt < 4; mt++)
        acc[mt][nt] = __builtin_amdgcn_mfma_f32_16x16x32_bf16(afr[mt], bfr, acc[mt][nt], 0, 0, 0);
    }
    if (pf){                          // write next step into inactive buffer
      *(uint4*)(Asn + wA0) = *(uint4*)na0;
      *(uint4*)(Asn + wA1) = *(uint4*)na1;
      *(uint4*)(Bsn + wA0) = nb0;
      *(uint4*)(Bsn + wA1) = nb1;
    }
    __syncthreads();                  // single barrier per K-step
  }
}

// K/V projection. z=0 -> Kb [b,h,t,d]; z=1 -> Vt [b,h,d,t] DIRECTLY
// (round-15: k_vt eliminated; verified round-21, absmax unchanged).
__global__ __launch_bounds__(256) void k_gemm_kv(
    const void* __restrict__ X, const u16* __restrict__ WkT,
    const u16* __restrict__ WvT, const u32* __restrict__ flg,
    u16* __restrict__ Kb, u16* __restrict__ Vt)
{
  __shared__ u16 lds[20480];          // 40960 B, double-buffered
  const int f = (int)flg[0];
  const u16* Bt = (blockIdx.z == 0) ? WkT : WvT;
  f32x4 acc[4][4];
  gemm_core_bt(X, f, Bt, lds, blockIdx.y, blockIdx.x, acc);
  const int tid = threadIdx.x, lane = tid & 63, w = tid >> 6;
  const int wm = w >> 1, wn = w & 1, quad = lane >> 4, l15 = lane & 15;
  if (blockIdx.z == 0){
    #pragma unroll
    for (int mt = 0; mt < 4; mt++)
      #pragma unroll
      for (int nt = 0; nt < 4; nt++)
        #pragma unroll
        for (int rr = 0; rr < 4; rr++){
          int m = blockIdx.y * 128 + wm * 64 + mt * 16 + quad * 4 + rr;
          int n = blockIdx.x * 128 + wn * 64 + nt * 16 + l15;
          int b = m >> 11, t = m & 2047, h = n >> 6, d = n & 63;
          Kb[((size_t)(b * 16 + h) * 2048 + t) * 64 + d] = f2bf(acc[mt][nt][rr]);
        }
  } else {
    #pragma unroll
    for (int mt = 0; mt < 4; mt++)
      #pragma unroll
      for (int nt = 0; nt < 4; nt++){
        u16 four[4];
        #pragma unroll
        for (int rr = 0; rr < 4; rr++) four[rr] = f2bf(acc[mt][nt][rr]);
        int m = blockIdx.y * 128 + wm * 64 + mt * 16 + quad * 4;   // rr = 0
        int n = blockIdx.x * 128 + wn * 64 + nt * 16 + l15;
        int b = m >> 11, t = m & 2047, h = n >> 6, d = n & 63;
        *(uint2*)(Vt + ((size_t)(b * 16 + h) * 64 + d) * 2048 + t) = *(uint2*)four;
      }
  }
}

// Output projection: AO(bf16) @ WoutT -> FP32 d_out.
__global__ __launch_bounds__(256) void k_gemm_out(
    const u16* __restrict__ A, const u16* __restrict__ WoutT,
    float* __restrict__ O)
{
  __shared__ u16 lds[20480];          // 40960 B, double-buffered
  f32x4 acc[4][4];
  gemm_core_bt(A, 0, WoutT, lds, blockIdx.y, blockIdx.x, acc);
  const int tid = threadIdx.x, lane = tid & 63, w = tid >> 6;
  const int wm = w >> 1, wn = w & 1, quad = lane >> 4, l15 = lane & 15;
  #pragma unroll
  for (int mt = 0; mt < 4; mt++)
    #pragma unroll
    for (int nt = 0; nt < 4; nt++)
      #pragma unroll
      for (int rr = 0; rr < 4; rr++){
        int m = blockIdx.y * 128 + wm * 64 + mt * 16 + quad * 4 + rr;
        int n = blockIdx.x * 128 + wn * 64 + nt * 16 + l15;
        O[(size_t)m * 1024 + n] = acc[mt][nt][rr];
      }
}

// ---------------------------------------------------------------------------
// MFMA causal flash v4 (REVERTED from v6: round-23 un-pairing regressed
// 59->78us, occupancy DROPPED 18.4->13.6% -- equal-length paired blocks
// keep CU residency and L2 streams coherent; pairing is load-bearing).
// Paired q-tiles {bx, 31-bx}: 33 kt-iters/block. Double-buffered K/V +
// async-stage split, 1 barrier/kt. Measured 52.2us (r13) / 59us (r21).
// ---------------------------------------------------------------------------
__global__ __launch_bounds__(256) void k_flash(
    const u8* __restrict__ Qidx, const float* __restrict__ Qrec,
    const u16* __restrict__ Kb, const u16* __restrict__ Vt,
    u16* __restrict__ AO)
{
  __shared__ u16 lds[23040];        // 46080 B
  u16* Ks0 = lds;                   // [64 key][72: d]
  u16* Ks1 = lds + 4608;
  u16* Vs0 = lds + 9216;            // [64 d][72: key]
  u16* Vs1 = lds + 13824;
  u16* Ps  = lds + 18432;           // 4 waves x [16 q][72: key] (wave-private)
  const int tid = threadIdx.x;
  const int lane = tid & 63, w = tid >> 6, quad = lane >> 4, l15 = lane & 15;
  const int bx = blockIdx.x, bh = blockIdx.y;
  const size_t baseK = (size_t)bh * (2048 * 64);
  const size_t baseV = (size_t)bh * (64 * 2048);
  const int sr = tid >> 3, sc = (tid & 7) * 8;
  const int b = bh >> 4, h = bh & 15;
  u16* Pw = Ps + w * (16 * 72);
  #pragma unroll
  for (int ph = 0; ph < 2; ph++){
    const int qt = ph ? (31 - bx) : bx;
    // Q fragments from the 240x64 reconstruction table
    const int qrowA = qt * 64 + w * 16 + l15;
    const int qi = Qidx[bh * 2048 + qrowA];
    const float* qr = Qrec + qi * 64;
    u16 qtmp[8];
    float4 qa = *(const float4*)(qr + quad * 8);
    float4 qb = *(const float4*)(qr + quad * 8 + 4);
    qtmp[0]=f2bf(qa.x); qtmp[1]=f2bf(qa.y); qtmp[2]=f2bf(qa.z); qtmp[3]=f2bf(qa.w);
    qtmp[4]=f2bf(qb.x); qtmp[5]=f2bf(qb.y); qtmp[6]=f2bf(qb.z); qtmp[7]=f2bf(qb.w);
    short8 aq0 = *(short8*)qtmp;
    qa = *(const float4*)(qr + 32 + quad * 8);
    qb = *(const float4*)(qr + 32 + quad * 8 + 4);
    qtmp[0]=f2bf(qa.x); qtmp[1]=f2bf(qa.y); qtmp[2]=f2bf(qa.z); qtmp[3]=f2bf(qa.w);
    qtmp[4]=f2bf(qb.x); qtmp[5]=f2bf(qb.y); qtmp[6]=f2bf(qb.z); qtmp[7]=f2bf(qb.w);
    short8 aq1 = *(short8*)qtmp;
    f32x4 o[4];
    #pragma unroll
    for (int nt = 0; nt < 4; nt++) o[nt] = (f32x4){0.f, 0.f, 0.f, 0.f};
    float lpart[4] = {0.f, 0.f, 0.f, 0.f};
    const int qrow_q = qt * 64 + w * 16 + quad * 4;
    // prologue: stage tile 0 into buffer 0 (direct). Safe vs the previous
    // phase: its loop ended with a barrier, epilogue touches no LDS.
    #pragma unroll
    for (int half = 0; half < 2; half++){
      int r = sr + half * 32;
      *(uint4*)(Ks0 + r * 72 + sc) =
          *(const uint4*)(Kb + baseK + (size_t)r * 64 + sc);
      *(uint4*)(Vs0 + r * 72 + sc) =
          *(const uint4*)(Vt + baseV + (size_t)r * 2048 + sc);
    }
    __syncthreads();
    for (int kt = 0; kt <= qt; kt++){
      const int kbase = kt * 64;
      const int cur = kt & 1;
      u16* Kc = cur ? Ks1 : Ks0;
      u16* Vc = cur ? Vs1 : Vs0;
      u16* Kn = cur ? Ks0 : Ks1;
      u16* Vn = cur ? Vs0 : Vs1;
      const bool pf = (kt < qt);
      uint4 kr0, kr1, vr0, vr1;
      if (pf){                       // issue next-tile loads EARLY (T14)
        const int nb = kbase + 64;
        kr0 = *(const uint4*)(Kb + baseK + (size_t)(nb + sr) * 64 + sc);
        kr1 = *(const uint4*)(Kb + baseK + (size_t)(nb + sr + 32) * 64 + sc);
        vr0 = *(const uint4*)(Vt + baseV + (size_t)sr * 2048 + nb + sc);
        vr1 = *(const uint4*)(Vt + baseV + (size_t)(sr + 32) * 2048 + nb + sc);
      }
      f32x4 s[4];
      #pragma unroll
      for (int nt = 0; nt < 4; nt++){
        s[nt] = (f32x4){0.f, 0.f, 0.f, 0.f};
        short8 bk0 = *(const short8*)(Kc + (nt * 16 + l15) * 72 + quad * 8);
        short8 bk1 = *(const short8*)(Kc + (nt * 16 + l15) * 72 + 32 + quad * 8);
        s[nt] = __builtin_amdgcn_mfma_f32_16x16x32_bf16(aq0, bk0, s[nt], 0, 0, 0);
        s[nt] = __builtin_amdgcn_mfma_f32_16x16x32_bf16(aq1, bk1, s[nt], 0, 0, 0);
      }
      if (kt == qt){
        #pragma unroll
        for (int rr = 0; rr < 4; rr++)
          #pragma unroll
          for (int nt = 0; nt < 4; nt++){
            float p = (kbase + nt * 16 + l15 > qrow_q + rr)
                        ? 0.f : __expf(s[nt][rr] * 0.125f - 16.0f);
            lpart[rr] += p;
            Pw[(quad * 4 + rr) * 72 + nt * 16 + l15] = f2bf(p);
          }
      } else {
        #pragma unroll
        for (int rr = 0; rr < 4; rr++)
          #pragma unroll
          for (int nt = 0; nt < 4; nt++){
            float p = __expf(s[nt][rr] * 0.125f - 16.0f);
            lpart[rr] += p;
            Pw[(quad * 4 + rr) * 72 + nt * 16 + l15] = f2bf(p);
          }
      }
      #pragma unroll
      for (int ks = 0; ks < 2; ks++){
        short8 pa = *(const short8*)(Pw + l15 * 72 + ks * 32 + quad * 8);
        #pragma unroll
        for (int nt = 0; nt < 4; nt++){
          short8 vbf = *(const short8*)(Vc + (nt * 16 + l15) * 72 + ks * 32 + quad * 8);
          o[nt] = __builtin_amdgcn_mfma_f32_16x16x32_bf16(pa, vbf, o[nt], 0, 0, 0);
        }
      }
      if (pf){                       // write next tile into inactive buffer
        *(uint4*)(Kn + sr * 72 + sc) = kr0;
        *(uint4*)(Kn + (sr + 32) * 72 + sc) = kr1;
        *(uint4*)(Vn + sr * 72 + sc) = vr0;
        *(uint4*)(Vn + (sr + 32) * 72 + sc) = vr1;
      }
      __syncthreads();               // single barrier per kt
    }
    // one-time l reduction across the 16 column-lanes
    float linv[4];
    #pragma unroll
    for (int rr = 0; rr < 4; rr++){
      float L = lpart[rr];
      L += __shfl_xor(L, 1); L += __shfl_xor(L, 2);
      L += __shfl_xor(L, 4); L += __shfl_xor(L, 8);
      linv[rr] = 1.0f / L;
    }
    #pragma unroll
    for (int rr = 0; rr < 4; rr++){
      int qrow = qrow_q + rr;
      #pragma unroll
      for (int nt = 0; nt < 4; nt++){
        float v = o[nt][rr] * linv[rr];
        AO[(size_t)(b * 2048 + qrow) * 1024 + h * 64 + nt * 16 + l15] = f2bf(v);
      }
    }
  }
}

extern "C" void kernel_launch(void* const* d_in, const int* in_sizes, int n_in,
                              void* d_out, int out_size, void* d_ws, size_t ws_size,
                              hipStream_t stream)
{
  int ix = -1, ibig[8], nbig = 0, i512[8], n512 = 0;
  for (int i = 0; i < n_in; i++){
    if (in_sizes[i] == 4194304) ix = i;
    else if (in_sizes[i] == 1048576){ if (nbig < 8) ibig[nbig++] = i; }
    else if (in_sizes[i] == 512){ if (n512 < 8) i512[n512++] = i; }
  }
  const void *x, *Wq, *Wk, *Wv, *Wout, *e8a, *e8b;
  if (ix >= 0 && nbig == 4 && n512 == 2){
    x = d_in[ix];
    e8a = d_in[i512[0]]; e8b = d_in[i512[1]];
    bool alpha = (i512[0] == 0 && i512[1] == 1 && ix == n_in - 1);
    if (alpha){
      Wk = d_in[ibig[0]]; Wout = d_in[ibig[1]];
      Wq = d_in[ibig[2]]; Wv   = d_in[ibig[3]];
    } else {
      Wq = d_in[ibig[0]]; Wk   = d_in[ibig[1]];
      Wv = d_in[ibig[2]]; Wout = d_in[ibig[3]];
    }
  } else {
    x = d_in[0]; Wq = d_in[1]; Wk = d_in[2]; Wv = d_in[3];
    e8a = d_in[4]; e8b = d_in[5]; Wout = d_in[6];
  }
  float* out = (float*)d_out;
  char* ws = (char*)d_ws;

  // ws layout -- 39 MB
  u32*   flg  = (u32*)  (ws);
  float* Qrec = (float*)(ws + 4096);
  u8*    Qidx = (u8*)   (ws + 69632);
  float* Wqe  = (float*)(ws + 147456);
  u16*   WT   = (u16*)  (ws + 1048576);
  u16*   Kb   = (u16*)  (ws + 7340032);
  u16*   Vt   = (u16*)  (ws + 24117248);
  u16*   AO   = (u16*)  (ws + 32505856);

  k_sniff<<<dim3(1), dim3(256), 0, stream>>>((const u16*)x, e8a, e8b, flg);
  k_prep_qrec<<<dim3(1), dim3(256), 0, stream>>>(e8a, e8b, flg, Qrec);
  k_prep_wqe<<<dim3(512), dim3(256), 0, stream>>>(Wq, e8a, e8b, flg, Wqe);
  k_qe8<<<dim3(1024), dim3(256), 0, stream>>>(x, flg, Wqe, Qidx);
  k_cvt_wT<<<dim3(256, 3), dim3(256), 0, stream>>>(Wk, Wv, Wout, flg, WT);
  k_gemm_kv<<<dim3(8, 32, 2), dim3(256), 0, stream>>>(
      x, WT, WT + 1048576, flg, Kb, Vt);
  k_flash<<<dim3(16, 32), dim3(256), 0, stream>>>(Qidx, Qrec, Kb, Vt, AO);
  k_gemm_out<<<dim3(8, 32), dim3(256), 0, stream>>>(AO, WT + 2097152, out);
}